// Round 5
// baseline (247.347 us; speedup 1.0000x reference)
//
#include <hip/hip_runtime.h>
#include <math.h>

#define IMG_H 1024
#define IMG_W 1024
#define IMG_B 8
#define TPB 128                    // 2 independent waves per block
#define RPB 16                     // output rows per band
#define BANDS (IMG_H / RPB)        // 64
#define NSTR 9                     // x-strips per row (stride 116, width 128)
#define STRIDE 116                 // interior px per strip
#define XHALO 6                    // px of x-halo each side (recomputed)
#define WPB (TPB / 64)
#define NBLK (IMG_B * BANDS * NSTR / WPB)   // 2304 blocks

__device__ __forceinline__ float sig2(float x) {   // sigmoid(2x) == sigmoid(x/EPS)
    return 1.0f / (1.0f + __expf(-2.0f * x));
}
__device__ __forceinline__ int imax(int a, int b) { return a > b ? a : b; }
__device__ __forceinline__ int imin(int a, int b) { return a < b ? a : b; }

// ---------------------------------------------------------------------------
// Depth-D row-pipelined kernel, wave-private 128-px x-strips, 2 px/lane.
// ZERO barriers, ZERO LDS: the only cross-thread values per stage are
// p0[x-1] (shfl_up of own px1) and u[x+1] (shfl_down of neighbor px0).
// x-halo 6/side is consumed 1 px/level (garbage from shfl at lane 0/63
// propagates inward <= 1 px per level; interior [6,122) stays exact).
// Strip-edge image semantics: ok-masked lanes get vf=0 (p contributions 0)
// and o=-1e30 (u = sig2(-inf) = 0), matching the reference zero padding.
// y-deps are per-lane register history exactly as before.
// ---------------------------------------------------------------------------
template<int D, bool READQ, bool FINAL>
__global__ __launch_bounds__(TPB, 4) void k_pipe(const float* __restrict__ qin,
                                                 const float* __restrict__ vf,
                                                 const float* __restrict__ o,
                                                 float* __restrict__ out) {
    const int gw    = blockIdx.x * WPB + (threadIdx.x >> 6);
    const int strip = gw % NSTR;
    const int bg    = gw / NSTR;
    const int band  = bg % BANDS;
    const int img   = bg / BANDS;
    const int lane  = threadIdx.x & 63;
    const int r0    = band * RPB;
    const int x     = strip * STRIDE - XHALO + lane * 2;      // even
    const bool ok   = ((unsigned)x < (unsigned)IMG_W);        // covers x and x+1
    const int  xc   = imin(imax(x, 0), IMG_W - 2);
    const bool inter = ok && (lane >= 3) && (lane <= 60);     // local px 6..121
    const size_t ibase = (size_t)img * IMG_H * IMG_W;

    constexpr int HALO = FINAL ? 1 : 0;
    constexpr int NOH  = FINAL ? D + 1 : D;

    const int u0lo = imax(r0 - (D - 1) - HALO, 0);
    const int ylo  = READQ ? imax(r0 - D - HALO, 0) : u0lo;
    const int yend = r0 + RPB - 1 + D;
    const int yhi  = imin(yend, IMG_H - 1);

    float qc[2], qz[2], qvPrev[2];
    float oh[NOH][2];
    float v0h[D + 1][2], v1h[D + 1][2];
    float uY[D][2], uZ[D][2];
    float p1prev[D + 1][2];
    float qsave[D][2];

#pragma unroll
    for (int j = 0; j < 2; ++j) {
        qc[j] = qz[j] = qvPrev[j] = 0.0f;
#pragma unroll
        for (int l = 0; l < NOH; ++l) oh[l][j] = 0.0f;
#pragma unroll
        for (int l = 0; l <= D; ++l) { v0h[l][j] = 0.0f; v1h[l][j] = 0.0f; p1prev[l][j] = 0.0f; }
#pragma unroll
        for (int l = 0; l < D; ++l) { uY[l][j] = 0.0f; uZ[l][j] = 0.0f; qsave[l][j] = 0.0f; }
    }

    const float* pQ = qin + ibase + (size_t)ylo * IMG_W + xc;
    const float* pO = o   + ibase + (size_t)ylo * IMG_W + xc;
    const float* pV = vf  + ((size_t)ylo * IMG_W + xc) * 2;

    for (int y = ylo; y <= yend; ++y) {
        // ---- shift row histories ----
#pragma unroll
        for (int k = NOH - 1; k >= 1; --k) { oh[k][0] = oh[k-1][0]; oh[k][1] = oh[k-1][1]; }
#pragma unroll
        for (int k = D; k >= 1; --k) {
            v0h[k][0] = v0h[k-1][0]; v0h[k][1] = v0h[k-1][1];
            v1h[k][0] = v1h[k-1][0]; v1h[k][1] = v1h[k-1][1];
        }
        if constexpr (READQ) { qz[0] = qc[0]; qz[1] = qc[1]; }

        // ---- load row y (clamped addr; ok-mask fixes semantics) ----
        if (y <= yhi) {
            if constexpr (READQ) {
                float2 q2 = *(const float2*)pQ; pQ += IMG_W;
                qc[0] = q2.x; qc[1] = q2.y;
            }
            float2 o2 = *(const float2*)pO; pO += IMG_W;
            oh[0][0] = ok ? o2.x : -1e30f;
            oh[0][1] = ok ? o2.y : -1e30f;
            float4 v4 = *(const float4*)pV; pV += 2 * IMG_W;
            v0h[0][0] = ok ? v4.x : 0.0f;  v1h[0][0] = ok ? v4.y : 0.0f;
            v0h[0][1] = ok ? v4.z : 0.0f;  v1h[0][1] = ok ? v4.w : 0.0f;
        } else {
            qc[0] = qc[1] = 0.0f;
            oh[0][0] = oh[0][1] = 0.0f;
            v0h[0][0] = v0h[0][1] = 0.0f;
            v1h[0][0] = v1h[0][1] = 0.0f;
        }

        // ---- level 0 ----
        if constexpr (READQ) {
            float p0c[2], p1c[2];
            p0c[0] = v0h[0][0] * qc[0];  p0c[1] = v0h[0][1] * qc[1];
            p1c[0] = v1h[0][0] * qc[0];  p1c[1] = v1h[0][1] * qc[1];
            const float pm1 = __shfl_up(p0c[1], 1);     // p0[x-1]
            if (y >= u0lo) {
#pragma unroll
                for (int j = 0; j < 2; ++j) {
                    float pl = (j == 0) ? pm1 : p0c[0];
                    float arg = oh[0][j] - (p1c[j] - p1prev[0][j] + p0c[j] - pl);
                    float nu = (y <= IMG_H - 1) ? sig2(arg) : 0.0f;
                    uZ[0][j] = uY[0][j]; uY[0][j] = nu;
                }
            }
            p1prev[0][0] = p1c[0]; p1prev[0][1] = p1c[1];
        } else {
#pragma unroll
            for (int j = 0; j < 2; ++j) {
                float nu = (y <= IMG_H - 1) ? sig2(oh[0][j]) : 0.0f;
                uZ[0][j] = uY[0][j]; uY[0][j] = nu;
            }
        }

        // ---- levels 1..D ----
#pragma unroll
        for (int l = 1; l <= D; ++l) {
            const int t = y - l;
            const int qlo = imax(r0 - (D - l) - HALO, 0);
            const bool qvalid = (t >= qlo) && (t <= IMG_H - 1);
            float qb[2], qv[2];
#pragma unroll
            for (int j = 0; j < 2; ++j)
                qb[j] = (l == 1) ? (READQ ? qz[j] : 0.0f) : qsave[l - 1][j];
            if (l >= 2) { qsave[l - 1][0] = qvPrev[0]; qsave[l - 1][1] = qvPrev[1]; }

            const float uRz = __shfl_down(uZ[l - 1][0], 1);   // u[t][x+2]
            if (qvalid) {
#pragma unroll
                for (int j = 0; j < 2; ++j) {
                    float gy = uY[l - 1][j] - uZ[l - 1][j];
                    float gx = ((j == 0) ? uZ[l - 1][1] : uRz) - uZ[l - 1][j];
                    qv[j] = fmaxf(qb[j] - 0.5f * (gy * v1h[l][j] + gx * v0h[l][j]), 0.0f);
                }
            } else {
                qv[0] = 0.0f; qv[1] = 0.0f;
            }

            if (l < D) {
                float p0p[2], p1p[2];
                p0p[0] = v0h[l][0] * qv[0];  p0p[1] = v0h[l][1] * qv[1];
                p1p[0] = v1h[l][0] * qv[0];  p1p[1] = v1h[l][1] * qv[1];
                const float pm1 = __shfl_up(p0p[1], 1);
                const int ulo = imax(r0 - (D - 1 - l) - HALO, 0);
                if (t >= ulo) {
#pragma unroll
                    for (int j = 0; j < 2; ++j) {
                        float pl = (j == 0) ? pm1 : p0p[0];
                        float arg = oh[l][j] - (p1p[j] - p1prev[l][j] + p0p[j] - pl);
                        float nu = (t <= IMG_H - 1) ? sig2(arg) : 0.0f;
                        uZ[l][j] = uY[l][j]; uY[l][j] = nu;
                    }
                }
                p1prev[l][0] = p1p[0]; p1prev[l][1] = p1p[1];
            } else {
                if constexpr (FINAL) {
                    float p0p[2], p1p[2];
                    p0p[0] = v0h[D][0] * qv[0];  p0p[1] = v0h[D][1] * qv[1];
                    p1p[0] = v1h[D][0] * qv[0];  p1p[1] = v1h[D][1] * qv[1];
                    const float pm1 = __shfl_up(p0p[1], 1);
                    if (t >= r0 && t < r0 + RPB) {
                        float r[2];
#pragma unroll
                        for (int j = 0; j < 2; ++j) {
                            float pl = (j == 0) ? pm1 : p0p[0];
                            float Tq = p1p[j] - p1prev[D][j] + p0p[j] - pl;
                            r[j] = 2.0f * (oh[D][j] - Tq);
                        }
                        if (inter)
                            *(float2*)(out + ibase + (size_t)t * IMG_W + x) =
                                make_float2(r[0], r[1]);
                    }
                    p1prev[D][0] = p1p[0]; p1prev[D][1] = p1p[1];
                } else {
                    if (t >= r0 && t < r0 + RPB && inter)
                        *(float2*)(out + ibase + (size_t)t * IMG_W + x) =
                            make_float2(qv[0], qv[1]);
                }
            }
            qvPrev[0] = qv[0]; qvPrev[1] = qv[1];
        }
    }
}

extern "C" void kernel_launch(void* const* d_in, const int* in_sizes, int n_in,
                              void* d_out, int out_size, void* d_ws, size_t ws_size,
                              hipStream_t stream) {
    const float* o  = (const float*)d_in[0];
    const float* vf = (const float*)d_in[1];
    float* qA = (float*)d_ws;

    // iterations 1..5: o,vf -> q5  (no q read)
    k_pipe<5, false, false><<<NBLK, TPB, 0, stream>>>(o, vf, o, qA);
    // iterations 6..10 + final: q5,o,vf -> out
    k_pipe<5, true,  true ><<<NBLK, TPB, 0, stream>>>(qA, vf, o, (float*)d_out);
}